// Round 8
// baseline (168.147 us; speedup 1.0000x reference)
//
#include <hip/hip_runtime.h>
#include <cstddef>

#define S_TOK 4096
#define CDIM 256
#define NHEADS 4
#define HDIM 64
#define LSK 72   // ushort stride for attention LDS rows
#define LDA 36   // ushort stride for GEMM LDS tiles (32 k + 4 pad)
#define LDY 264  // float stride for GEMM2 LN buffer
#define LOG2E 1.44269504f

typedef __attribute__((ext_vector_type(8))) short short8;
typedef __attribute__((ext_vector_type(4))) float floatx4;

__device__ inline unsigned short f2bf(float f) {
  union { float f; unsigned u; } v;
  v.f = f;
  unsigned r = v.u + 0x7fff + ((v.u >> 16) & 1);  // round-to-nearest-even
  return (unsigned short)(r >> 16);
}
__device__ inline float bf2f(unsigned short u) {
  union { unsigned u; float f; } v;
  v.u = ((unsigned)u) << 16;
  return v.f;
}
// pack two floats to bf16x2 (low = a). gfx950 HW convert if available.
__device__ inline unsigned pack_bf16(float a, float b) {
#if __has_builtin(__builtin_amdgcn_cvt_pk_bf16_f32)
  typedef __bf16 bf16x2 __attribute__((ext_vector_type(2)));
  union { bf16x2 v; unsigned u; } r;
  r.v = __builtin_amdgcn_cvt_pk_bf16_f32(a, b);
  return r.u;
#else
  return ((unsigned)f2bf(b) << 16) | f2bf(a);
#endif
}

// ---------------- Prep: weights fp32->bf16 (blocks 0..255) + x transpose -----
__global__ __launch_bounds__(256) void prep_kernel(
    const float* __restrict__ x, const float* __restrict__ ipw,
    const float* __restrict__ ow, unsigned short* __restrict__ wbf,
    unsigned short* __restrict__ owbf, unsigned short* __restrict__ xbfT) {
  __shared__ __align__(16) unsigned short T[64 * 72];
  const int tid = threadIdx.x;
  if (blockIdx.x < 256) {  // weight conversion: 65536 float4s
    int idx = blockIdx.x * 256 + tid;
    float4 f;
    unsigned short* dst;
    if (idx < 49152) {
      f = ((const float4*)ipw)[idx];
      dst = wbf + idx * 4;
    } else {
      int j = idx - 49152;
      f = ((const float4*)ow)[j];
      dst = owbf + j * 4;
    }
    ushort4 u;
    u.x = f2bf(f.x); u.y = f2bf(f.y); u.z = f2bf(f.z); u.w = f2bf(f.w);
    *(ushort4*)dst = u;
    return;
  }
  const int bid = blockIdx.x - 256;
  const int s0 = (bid & 63) * 64, c0 = ((bid >> 6) & 3) * 64, b = bid >> 8;
  const int c_l = tid >> 2, q4 = tid & 3;
  const float4* src = (const float4*)(x + (((size_t)(b * CDIM + c0 + c_l)) << 12) + s0);
#pragma unroll
  for (int i = 0; i < 4; ++i) {
    int chunk = i * 4 + q4;
    float4 f = src[chunk];
    T[(chunk * 4 + 0) * 72 + c_l] = f2bf(f.x);
    T[(chunk * 4 + 1) * 72 + c_l] = f2bf(f.y);
    T[(chunk * 4 + 2) * 72 + c_l] = f2bf(f.z);
    T[(chunk * 4 + 3) * 72 + c_l] = f2bf(f.w);
  }
  __syncthreads();
  const int s_l = tid >> 2;
  unsigned short* drow = xbfT + ((size_t)((b << 12) + s0 + s_l)) * CDIM + c0;
#pragma unroll
  for (int i = 0; i < 2; ++i) {
    int chunk = i * 4 + q4;
    uint4 u = *(const uint4*)&T[s_l * 72 + chunk * 8];
    *(uint4*)(drow + chunk * 8) = u;
  }
}

// ---------------- Kernel 1: QKV projection, bf16 MFMA GEMM (128x64 tiles) ----
__global__ __launch_bounds__(256) void qkv_gemm_kernel(
    const unsigned short* __restrict__ xbfT, const unsigned short* __restrict__ wbf,
    const float* __restrict__ ipb, unsigned short* __restrict__ q16,
    unsigned short* __restrict__ k16, unsigned short* __restrict__ vt16) {
  __shared__ __align__(16) unsigned short As[128 * LDA];  // [tok_l][k_l]
  __shared__ __align__(16) unsigned short Bs[64 * LDA];   // [cout_l][k_l]
  const int tid = threadIdx.x;
  const int wave = tid >> 6, lane = tid & 63;
  const int quad = lane >> 4, l16 = lane & 15;
  const int n0 = blockIdx.x * 64;    // c_out base (0..704)
  const int tok0 = blockIdx.y * 128; // token base within batch
  const int b = blockIdx.z;

  const int r1 = tid >> 2, c1 = tid & 3;
  const unsigned short* gA = xbfT + ((size_t)(b * S_TOK + tok0 + r1)) * CDIM + c1 * 8;
  const unsigned short* gB = wbf + ((size_t)(n0 + r1)) * CDIM + c1 * 8;
  unsigned short* wA = &As[r1 * LDA + c1 * 8];
  unsigned short* wB = &Bs[r1 * LDA + c1 * 8];

  floatx4 acc[2][4];
#pragma unroll
  for (int mt = 0; mt < 2; ++mt)
#pragma unroll
    for (int nt = 0; nt < 4; ++nt) acc[mt][nt] = (floatx4){0.f, 0.f, 0.f, 0.f};

  uint4 a0p = *(const uint4*)(gA);
  uint4 a1p = *(const uint4*)(gA + 64 * CDIM);
  uint4 b0p = *(const uint4*)(gB);

  for (int ks = 0; ks < 8; ++ks) {
    __syncthreads();
    *(uint4*)wA = a0p;
    *(uint4*)(wA + 64 * LDA) = a1p;
    *(uint4*)wB = b0p;
    __syncthreads();
    if (ks < 7) {
      int off = (ks + 1) * 32;
      a0p = *(const uint4*)(gA + off);
      a1p = *(const uint4*)(gA + 64 * CDIM + off);
      b0p = *(const uint4*)(gB + off);
    }
    short8 af[2], bf[4];
#pragma unroll
    for (int mt = 0; mt < 2; ++mt)
      af[mt] = *(const short8*)&As[(wave * 32 + mt * 16 + l16) * LDA + quad * 8];
#pragma unroll
    for (int nt = 0; nt < 4; ++nt)
      bf[nt] = *(const short8*)&Bs[(nt * 16 + l16) * LDA + quad * 8];
#pragma unroll
    for (int mt = 0; mt < 2; ++mt)
#pragma unroll
      for (int nt = 0; nt < 4; ++nt)
        acc[mt][nt] = __builtin_amdgcn_mfma_f32_16x16x32_bf16(af[mt], bf[nt], acc[mt][nt], 0, 0, 0);
  }

  const int slab = n0 >> 8;  // 0=q, 1=k, 2=v
  int cb[4];
  float bias4[4];
#pragma unroll
  for (int nt = 0; nt < 4; ++nt) {
    cb[nt] = n0 + nt * 16 + l16;
    bias4[nt] = ipb[cb[nt]];
  }
  if (slab == 2) {  // v -> vt16[bh][dh][tok]
#pragma unroll
    for (int mt = 0; mt < 2; ++mt) {
      int tok = tok0 + wave * 32 + mt * 16 + quad * 4;
#pragma unroll
      for (int nt = 0; nt < 4; ++nt) {
        int dh = cb[nt] & 63, h = (cb[nt] >> 6) & 3;
        uint2 u;
        u.x = pack_bf16(acc[mt][nt][0] + bias4[nt], acc[mt][nt][1] + bias4[nt]);
        u.y = pack_bf16(acc[mt][nt][2] + bias4[nt], acc[mt][nt][3] + bias4[nt]);
        *(uint2*)&vt16[((size_t)((b * NHEADS + h) * HDIM + dh)) * S_TOK + tok] = u;
      }
    }
  } else {
    unsigned short* dst = slab ? k16 : q16;
    const float sc = slab ? 1.0f : 0.125f * LOG2E;
#pragma unroll
    for (int mt = 0; mt < 2; ++mt)
#pragma unroll
      for (int nt = 0; nt < 4; ++nt) {
        int dh = cb[nt] & 63, h = (cb[nt] >> 6) & 3;
        size_t base = ((size_t)(b * NHEADS + h) * S_TOK);
#pragma unroll
        for (int r = 0; r < 4; ++r) {
          int tok = tok0 + wave * 32 + mt * 16 + quad * 4 + r;
          dst[(base + tok) * HDIM + dh] = f2bf((acc[mt][nt][r] + bias4[nt]) * sc);
        }
      }
  }
}

// ---------------- Kernel 2: flash attention, S^T trick, mt=4, 4-way split ----
// Wave owns 64 q-rows (4 m-tiles): K/V frags + staging amortized 4x.
// S^T = mfma(kf, qf) -> lane's 4 values = 4 consecutive keys of one q-row ->
// one b64 store into Ps[qrow][key]. HW packed bf16 convert. 2 blocks/CU.
__global__ __launch_bounds__(256) void attn_kernel(
    const unsigned short* __restrict__ q16,
    const unsigned short* __restrict__ k16,
    const unsigned short* __restrict__ vt16,
    unsigned short* __restrict__ op, float* __restrict__ lp) {
  __shared__ __align__(16) unsigned short Ks[64 * LSK];      // [key][dd]
  __shared__ __align__(16) unsigned short Vt[64 * LSK];      // [d][key]
  __shared__ __align__(16) unsigned short Ps[4 * 64 * LSK];  // per-wave [qrow][key]

  const int tid = threadIdx.x;
  const int wave = tid >> 6;
  const int lane = tid & 63;
  const int quad = lane >> 4;
  const int l16 = lane & 15;
  const int bh = blockIdx.y;
  const int q0 = blockIdx.x * 256;
  const int split = blockIdx.z;
  const int kt0 = split * 16;

  // Q fragments for 4 m-tiles (loop-invariant)
  short8 qf[4][2];
#pragma unroll
  for (int mt = 0; mt < 4; ++mt) {
    const unsigned short* qg =
        q16 + ((size_t)bh * S_TOK + q0 + wave * 64 + mt * 16 + l16) * HDIM + quad * 8;
    qf[mt][0] = *(const short8*)(qg);
    qf[mt][1] = *(const short8*)(qg + 32);
  }

  const int sr = tid >> 3, scc = tid & 7;
  const unsigned short* kg = k16 + ((size_t)bh * S_TOK + sr) * HDIM + scc * 8;
  const unsigned short* vg = vt16 + ((size_t)bh * HDIM + sr) * S_TOK + scc * 8;
  unsigned short* ksw = &Ks[sr * LSK + scc * 8];
  unsigned short* vtw = &Vt[sr * LSK + scc * 8];

  floatx4 O[4][4];
  float lsum[4] = {0.f, 0.f, 0.f, 0.f};
#pragma unroll
  for (int mt = 0; mt < 4; ++mt)
#pragma unroll
    for (int nt = 0; nt < 4; ++nt) O[mt][nt] = (floatx4){0.f, 0.f, 0.f, 0.f};

  uint4 k0r = *(const uint4*)(kg + (size_t)kt0 * 64 * HDIM);
  uint4 k1r = *(const uint4*)(kg + (size_t)kt0 * 64 * HDIM + 32 * HDIM);
  uint4 v0r = *(const uint4*)(vg + kt0 * 64);
  uint4 v1r = *(const uint4*)(vg + kt0 * 64 + (size_t)32 * S_TOK);

  unsigned short* pw = &Ps[(wave * 64) * LSK];

  for (int t = 0; t < 16; ++t) {
    __syncthreads();
    *(uint4*)ksw = k0r;
    *(uint4*)(ksw + 32 * LSK) = k1r;
    *(uint4*)vtw = v0r;
    *(uint4*)(vtw + 32 * LSK) = v1r;
    __syncthreads();
    if (t < 15) {
      const unsigned short* kgn = kg + (size_t)(kt0 + t + 1) * 64 * HDIM;
      const unsigned short* vgn = vg + (kt0 + t + 1) * 64;
      k0r = *(const uint4*)(kgn);
      k1r = *(const uint4*)(kgn + 32 * HDIM);
      v0r = *(const uint4*)(vgn);
      v1r = *(const uint4*)(vgn + (size_t)32 * S_TOK);
    }

    // ---- S^T = K Q^T per (kt16, mt); exp2 + packed b64 store to Ps[qrow][key]
#pragma unroll
    for (int kt = 0; kt < 4; ++kt) {
      short8 kf0 = *(const short8*)(&Ks[(kt * 16 + l16) * LSK + quad * 8]);
      short8 kf1 = *(const short8*)(&Ks[(kt * 16 + l16) * LSK + 32 + quad * 8]);
#pragma unroll
      for (int mt = 0; mt < 4; ++mt) {
        floatx4 c = (floatx4){0.f, 0.f, 0.f, 0.f};
        c = __builtin_amdgcn_mfma_f32_16x16x32_bf16(kf0, qf[mt][0], c, 0, 0, 0);
        c = __builtin_amdgcn_mfma_f32_16x16x32_bf16(kf1, qf[mt][1], c, 0, 0, 0);
        float p0 = __builtin_amdgcn_exp2f(c[0]);
        float p1 = __builtin_amdgcn_exp2f(c[1]);
        float p2 = __builtin_amdgcn_exp2f(c[2]);
        float p3 = __builtin_amdgcn_exp2f(c[3]);
        lsum[mt] += (p0 + p1) + (p2 + p3);
        uint2 pk;
        pk.x = pack_bf16(p0, p1);
        pk.y = pack_bf16(p2, p3);
        *(uint2*)&pw[(mt * 16 + l16) * LSK + kt * 16 + quad * 4] = pk;
      }
    }

    // ---- O += P V ; V-frags shared across all 4 m-tiles
    short8 pf[4][2];
#pragma unroll
    for (int mt = 0; mt < 4; ++mt) {
      pf[mt][0] = *(const short8*)(&pw[(mt * 16 + l16) * LSK + quad * 8]);
      pf[mt][1] = *(const short8*)(&pw[(mt * 16 + l16) * LSK + 32 + quad * 8]);
    }
#pragma unroll
    for (int nt = 0; nt < 4; ++nt) {
      short8 vf0 = *(const short8*)(&Vt[(nt * 16 + l16) * LSK + quad * 8]);
      short8 vf1 = *(const short8*)(&Vt[(nt * 16 + l16) * LSK + 32 + quad * 8]);
#pragma unroll
      for (int mt = 0; mt < 4; ++mt) {
        O[mt][nt] = __builtin_amdgcn_mfma_f32_16x16x32_bf16(pf[mt][0], vf0, O[mt][nt], 0, 0, 0);
        O[mt][nt] = __builtin_amdgcn_mfma_f32_16x16x32_bf16(pf[mt][1], vf1, O[mt][nt], 0, 0, 0);
      }
    }
  }

  // epilogue: partials in ab-layout; l-partials per (bh,row)
  const int b = bh >> 2, h = bh & 3;
  unsigned short* op_s = op + (size_t)split * 2097152;
  float* lp_s = lp + (size_t)split * 32768;
#pragma unroll
  for (int mt = 0; mt < 4; ++mt) {
    float ls = lsum[mt];
    ls += __shfl_xor(ls, 16);
    ls += __shfl_xor(ls, 32);
    if (quad == 0)
      lp_s[bh * S_TOK + q0 + wave * 64 + mt * 16 + l16] = ls;
#pragma unroll
    for (int r = 0; r < 4; ++r) {
      int row = q0 + wave * 64 + mt * 16 + quad * 4 + r;
#pragma unroll
      for (int nt = 0; nt < 4; ++nt)
        op_s[((size_t)(b * S_TOK + row)) * CDIM + h * HDIM + nt * 16 + l16] =
            f2bf(O[mt][nt][r]);
    }
  }
}

// merged A-element: sum 4 split partials, scale by 1/l, pack 2 bf16
__device__ inline unsigned merge2(const unsigned short* op, size_t off, float rinv) {
  float lo = 0.f, hi = 0.f;
#pragma unroll
  for (int sp = 0; sp < 4; ++sp) {
    unsigned u = *(const unsigned*)(op + (size_t)sp * 2097152 + off);
    lo += bf2f((unsigned short)(u & 0xffff));
    hi += bf2f((unsigned short)(u >> 16));
  }
  return pack_bf16(lo * rinv, hi * rinv);
}

// ---------------- Kernel 3: merge + out projection (MFMA) + LayerNorm --------
__global__ __launch_bounds__(256) void out_ln_gemm_kernel(
    const unsigned short* __restrict__ op, const float* __restrict__ lp,
    const unsigned short* __restrict__ owbf, const float* __restrict__ obias,
    const float* __restrict__ lng, const float* __restrict__ lnb,
    float* __restrict__ out) {
  __shared__ __align__(16) unsigned short As[16 * LDA];
  __shared__ __align__(16) unsigned short Bs[256 * LDA];
  __shared__ __align__(16) float ys[16 * LDY];
  __shared__ float rsum[64];  // [tok_l][h]
  const int tid = threadIdx.x;
  const int wave = tid >> 6, lane = tid & 63;
  const int quad = lane >> 4, l16 = lane & 15;
  const int tok0 = blockIdx.x * 16;  // global token (b folded)

  if (tid < 64) {
    int t = tid >> 2, h = tid & 3;
    int bb = tok0 >> 12;
    int idx = (bb * 4 + h) * 4096 + (tok0 & 4095) + t;
    rsum[t * 4 + h] =
        1.0f / (lp[idx] + lp[32768 + idx] + lp[65536 + idx] + lp[98304 + idx]);
  }
  __syncthreads();

  const int ar = tid >> 4, ac = tid & 15;
  const size_t abase = (size_t)(tok0 + ar) * CDIM + ac * 2;
  unsigned short* wAp = &As[ar * LDA + ac * 2];
  const int br = tid >> 2, bc = tid & 3;
  const unsigned short* gB = owbf + ((size_t)br) * CDIM + bc * 8;
  unsigned short* wBp = &Bs[br * LDA + bc * 8];

  floatx4 acc[4];
#pragma unroll
  for (int nt = 0; nt < 4; ++nt) acc[nt] = (floatx4){0.f, 0.f, 0.f, 0.f};

  unsigned ap = merge2(op, abase, rsum[ar * 4]);
  uint4 bp[4];
#pragma unroll
  for (int i = 0; i < 4; ++i) bp[i] = *(const uint4*)(gB + (size_t)i * 64 * CDIM);

  for (int ks = 0; ks < 8; ++ks) {
    __syncthreads();
    *(unsigned*)wAp = ap;
#pragma unroll
    for (int i = 0; i < 4; ++i) *(uint4*)(wBp + i * 64 * LDA) = bp[i];
    __syncthreads();
    if (ks < 7) {
      int off = (ks + 1) * 32;
      ap = merge2(op, abase + off, rsum[ar * 4 + ((ks + 1) >> 1)]);
#pragma unroll
      for (int i = 0; i < 4; ++i)
        bp[i] = *(const uint4*)(gB + (size_t)i * 64 * CDIM + off);
    }
    short8 af = *(const short8*)&As[l16 * LDA + quad * 8];
    short8 bf[4];
#pragma unroll
    for (int nt = 0; nt < 4; ++nt)
      bf[nt] = *(const short8*)&Bs[(wave * 64 + nt * 16 + l16) * LDA + quad * 8];
#pragma unroll
    for (int nt = 0; nt < 4; ++nt)
      acc[nt] = __builtin_amdgcn_mfma_f32_16x16x32_bf16(af, bf[nt], acc[nt], 0, 0, 0);
  }

#pragma unroll
  for (int nt = 0; nt < 4; ++nt) {
    int c = wave * 64 + nt * 16 + l16;
    float bo = obias[c];
#pragma unroll
    for (int r = 0; r < 4; ++r)
      ys[(quad * 4 + r) * LDY + c] = acc[nt][r] + bo;
  }
  __syncthreads();

  const int gtok = tid >> 4, lx = tid & 15;
  float sum = 0.f, ssq = 0.f;
#pragma unroll
  for (int i = 0; i < 16; ++i) {
    float v = ys[gtok * LDY + i * 16 + lx];
    sum += v;
    ssq += v * v;
  }
  sum += __shfl_xor(sum, 1); ssq += __shfl_xor(ssq, 1);
  sum += __shfl_xor(sum, 2); ssq += __shfl_xor(ssq, 2);
  sum += __shfl_xor(sum, 4); ssq += __shfl_xor(ssq, 4);
  sum += __shfl_xor(sum, 8); ssq += __shfl_xor(ssq, 8);
  float mu = sum * (1.f / 256.f);
  float var = ssq * (1.f / 256.f) - mu * mu;
  float rstd = rsqrtf(var + 1e-5f);
  const int b2 = tok0 >> 12;
  const int sl = (tok0 & 4095) + gtok;
#pragma unroll
  for (int i = 0; i < 16; ++i) {
    int c = i * 16 + lx;
    float v = ys[gtok * LDY + c];
    out[(((size_t)(b2 * CDIM + c)) << 12) + sl] = (v - mu) * rstd * lng[c] + lnb[c];
  }
}

extern "C" void kernel_launch(void* const* d_in, const int* in_sizes, int n_in,
                              void* d_out, int out_size, void* d_ws, size_t ws_size,
                              hipStream_t stream) {
  const float* x = (const float*)d_in[0];
  const float* ipw = (const float*)d_in[1];
  const float* ipb = (const float*)d_in[2];
  const float* ow = (const float*)d_in[3];
  const float* ob = (const float*)d_in[4];
  const float* lng = (const float*)d_in[5];
  const float* lnb = (const float*)d_in[6];
  float* out = (float*)d_out;
  // workspace (ushort units), total ~34.6 MiB:
  unsigned short* wbf = (unsigned short*)d_ws;       // 196608
  unsigned short* owbf = wbf + 196608;               // 65536
  unsigned short* xbfT = owbf + 65536;               // 2097152
  unsigned short* q16 = xbfT + 2097152;              // 2097152
  unsigned short* k16 = q16 + 2097152;               // 2097152
  unsigned short* vt16 = k16 + 2097152;              // 2097152
  unsigned short* op = vt16 + 2097152;               // 4 x 2097152 (ab-layout partials)
  float* lp = (float*)(op + 8388608);                // 4 x 32768 fp32

  prep_kernel<<<768, 256, 0, stream>>>(x, ipw, ow, wbf, owbf, xbfT);
  qkv_gemm_kernel<<<dim3(12, 32, 2), 256, 0, stream>>>(xbfT, wbf, ipb, q16, k16, vt16);
  attn_kernel<<<dim3(16, 8, 4), 256, 0, stream>>>(q16, k16, vt16, op, lp);
  out_ln_gemm_kernel<<<512, 256, 0, stream>>>(op, lp, owbf, ob, lng, lnb, out);
}

// Round 9
// 149.580 us; speedup vs baseline: 1.1241x; 1.1241x over previous
//
#include <hip/hip_runtime.h>
#include <cstddef>

#define S_TOK 4096
#define CDIM 256
#define NHEADS 4
#define HDIM 64
#define LSK 72   // ushort stride for attention LDS rows
#define LDA 36   // ushort stride for GEMM LDS tiles (32 k + 4 pad)
#define LDY 264  // float stride for LN buffer
#define LOG2E 1.44269504f

typedef __attribute__((ext_vector_type(8))) short short8;
typedef __attribute__((ext_vector_type(4))) float floatx4;

__device__ inline unsigned short f2bf(float f) {
  union { float f; unsigned u; } v;
  v.f = f;
  unsigned r = v.u + 0x7fff + ((v.u >> 16) & 1);  // round-to-nearest-even
  return (unsigned short)(r >> 16);
}
__device__ inline float bf2f(unsigned short u) {
  union { unsigned u; float f; } v;
  v.u = ((unsigned)u) << 16;
  return v.f;
}
// pack two floats to bf16x2 (low = a). gfx950 HW convert if available.
__device__ inline unsigned pack_bf16(float a, float b) {
#if __has_builtin(__builtin_amdgcn_cvt_pk_bf16_f32)
  typedef __bf16 bf16x2 __attribute__((ext_vector_type(2)));
  union { bf16x2 v; unsigned u; } r;
  r.v = __builtin_amdgcn_cvt_pk_bf16_f32(a, b);
  return r.u;
#else
  return ((unsigned)f2bf(b) << 16) | f2bf(a);
#endif
}

// ---------------- Kernel 1: fused QKV GEMM, fp32 inputs staged to bf16 -------
// Block: 64 tokens x 64 dh-channels x {q,k,v} (3 B-tiles share one A-tile).
// A staged directly from x (b,C,S) fp32: k-slab = 32 contiguous rows.
// B staged directly from in_proj_w fp32. q prescale = (1/8)*log2e.
__global__ __launch_bounds__(256) void qkv_gemm_kernel(
    const float* __restrict__ x, const float* __restrict__ ipw,
    const float* __restrict__ ipb, unsigned short* __restrict__ q16,
    unsigned short* __restrict__ k16, unsigned short* __restrict__ vt16) {
  __shared__ __align__(16) unsigned short As[64 * LDA];     // [tok_l][k_l]
  __shared__ __align__(16) unsigned short Bs[3][64 * LDA];  // [slab][dh_l][k_l]
  const int tid = threadIdx.x;
  const int wave = tid >> 6, lane = tid & 63;
  const int quad = lane >> 4, l16 = lane & 15;
  const int n0 = blockIdx.x * 64;   // dh-block within slab (0..192)
  const int tok0 = blockIdx.y * 64; // token base within batch
  const int b = blockIdx.z;

  // A staging: thread = (channel c_l 0..31, token-octet t8 0..7)
  const int c_l = tid >> 3, t8 = tid & 7;
  const float* gx = x + (((size_t)(b * CDIM + c_l)) << 12) + tok0 + t8 * 8;
  unsigned short* wa = &As[(t8 * 8) * LDA + c_l];

  // B staging: thread = (row rr 0..63, k-chunk c4 0..3) x 3 slabs
  const int rr = tid >> 2, c4 = tid & 3;
  const float* gw0 = ipw + ((size_t)(n0 + rr)) * CDIM + c4 * 8;
  unsigned short* wb0 = &Bs[0][rr * LDA + c4 * 8];

  floatx4 acc[3][4];
#pragma unroll
  for (int s = 0; s < 3; ++s)
#pragma unroll
    for (int nt = 0; nt < 4; ++nt) acc[s][nt] = (floatx4){0.f, 0.f, 0.f, 0.f};

  // prefetch ks=0
  float4 a0 = *(const float4*)(gx);
  float4 a1 = *(const float4*)(gx + 4);
  float4 bp[3][2];
#pragma unroll
  for (int s = 0; s < 3; ++s) {
    bp[s][0] = *(const float4*)(gw0 + (size_t)s * 256 * CDIM);
    bp[s][1] = *(const float4*)(gw0 + (size_t)s * 256 * CDIM + 4);
  }

  for (int ks = 0; ks < 8; ++ks) {
    __syncthreads();
    // A -> LDS: 8 bf16 scalar writes (pairs via HW pack)
    {
      unsigned p;
      p = pack_bf16(a0.x, a0.y);
      wa[0 * LDA] = (unsigned short)p; wa[1 * LDA] = (unsigned short)(p >> 16);
      p = pack_bf16(a0.z, a0.w);
      wa[2 * LDA] = (unsigned short)p; wa[3 * LDA] = (unsigned short)(p >> 16);
      p = pack_bf16(a1.x, a1.y);
      wa[4 * LDA] = (unsigned short)p; wa[5 * LDA] = (unsigned short)(p >> 16);
      p = pack_bf16(a1.z, a1.w);
      wa[6 * LDA] = (unsigned short)p; wa[7 * LDA] = (unsigned short)(p >> 16);
    }
    // B -> LDS: 2x 8B writes per slab
#pragma unroll
    for (int s = 0; s < 3; ++s) {
      uint2 u0, u1;
      u0.x = pack_bf16(bp[s][0].x, bp[s][0].y);
      u0.y = pack_bf16(bp[s][0].z, bp[s][0].w);
      u1.x = pack_bf16(bp[s][1].x, bp[s][1].y);
      u1.y = pack_bf16(bp[s][1].z, bp[s][1].w);
      unsigned short* w = wb0 + s * 64 * LDA;
      *(uint2*)w = u0;
      *(uint2*)(w + 4) = u1;
    }
    __syncthreads();
    if (ks < 7) {  // prefetch next k-slab
      const float* gxn = gx + ((size_t)((ks + 1) * 32) << 12);
      a0 = *(const float4*)(gxn);
      a1 = *(const float4*)(gxn + 4);
#pragma unroll
      for (int s = 0; s < 3; ++s) {
        const float* g = gw0 + (size_t)s * 256 * CDIM + (ks + 1) * 32;
        bp[s][0] = *(const float4*)(g);
        bp[s][1] = *(const float4*)(g + 4);
      }
    }
    short8 af = *(const short8*)&As[(wave * 16 + l16) * LDA + quad * 8];
#pragma unroll
    for (int s = 0; s < 3; ++s)
#pragma unroll
      for (int nt = 0; nt < 4; ++nt) {
        short8 bf = *(const short8*)&Bs[s][(nt * 16 + l16) * LDA + quad * 8];
        acc[s][nt] = __builtin_amdgcn_mfma_f32_16x16x32_bf16(af, bf, acc[s][nt], 0, 0, 0);
      }
  }

  // epilogue
  const float qsc = 0.125f * LOG2E;
#pragma unroll
  for (int nt = 0; nt < 4; ++nt) {
    int cb = n0 + nt * 16 + l16;       // channel within slab, 0..255
    int h = cb >> 6, dh = cb & 63;
    float bq = ipb[cb], bk = ipb[256 + cb], bv = ipb[512 + cb];
    size_t base = ((size_t)(b * NHEADS + h)) * S_TOK;
#pragma unroll
    for (int r = 0; r < 4; ++r) {
      int tok = tok0 + wave * 16 + quad * 4 + r;
      q16[(base + tok) * HDIM + dh] = f2bf((acc[0][nt][r] + bq) * qsc);
      k16[(base + tok) * HDIM + dh] = f2bf(acc[1][nt][r] + bk);
    }
    int tokv = tok0 + wave * 16 + quad * 4;
    uint2 u;
    u.x = pack_bf16(acc[2][nt][0] + bv, acc[2][nt][1] + bv);
    u.y = pack_bf16(acc[2][nt][2] + bv, acc[2][nt][3] + bv);
    *(uint2*)&vt16[(base * 0 + ((size_t)(b * NHEADS + h) * HDIM + dh)) * S_TOK + tokv] = u;
  }
}

// ---------------- Kernel 2: flash attention, S^T trick, mt=4, 4-way split ----
__global__ __launch_bounds__(256) void attn_kernel(
    const unsigned short* __restrict__ q16,
    const unsigned short* __restrict__ k16,
    const unsigned short* __restrict__ vt16,
    unsigned short* __restrict__ op, float* __restrict__ lp) {
  __shared__ __align__(16) unsigned short Ks[64 * LSK];      // [key][dd]
  __shared__ __align__(16) unsigned short Vt[64 * LSK];      // [d][key]
  __shared__ __align__(16) unsigned short Ps[4 * 64 * LSK];  // per-wave [qrow][key]

  const int tid = threadIdx.x;
  const int wave = tid >> 6;
  const int lane = tid & 63;
  const int quad = lane >> 4;
  const int l16 = lane & 15;
  const int bh = blockIdx.y;
  const int q0 = blockIdx.x * 256;
  const int split = blockIdx.z;
  const int kt0 = split * 16;

  short8 qf[4][2];
#pragma unroll
  for (int mt = 0; mt < 4; ++mt) {
    const unsigned short* qg =
        q16 + ((size_t)bh * S_TOK + q0 + wave * 64 + mt * 16 + l16) * HDIM + quad * 8;
    qf[mt][0] = *(const short8*)(qg);
    qf[mt][1] = *(const short8*)(qg + 32);
  }

  const int sr = tid >> 3, scc = tid & 7;
  const unsigned short* kg = k16 + ((size_t)bh * S_TOK + sr) * HDIM + scc * 8;
  const unsigned short* vg = vt16 + ((size_t)bh * HDIM + sr) * S_TOK + scc * 8;
  unsigned short* ksw = &Ks[sr * LSK + scc * 8];
  unsigned short* vtw = &Vt[sr * LSK + scc * 8];

  floatx4 O[4][4];
  float lsum[4] = {0.f, 0.f, 0.f, 0.f};
#pragma unroll
  for (int mt = 0; mt < 4; ++mt)
#pragma unroll
    for (int nt = 0; nt < 4; ++nt) O[mt][nt] = (floatx4){0.f, 0.f, 0.f, 0.f};

  uint4 k0r = *(const uint4*)(kg + (size_t)kt0 * 64 * HDIM);
  uint4 k1r = *(const uint4*)(kg + (size_t)kt0 * 64 * HDIM + 32 * HDIM);
  uint4 v0r = *(const uint4*)(vg + kt0 * 64);
  uint4 v1r = *(const uint4*)(vg + kt0 * 64 + (size_t)32 * S_TOK);

  unsigned short* pw = &Ps[(wave * 64) * LSK];

  for (int t = 0; t < 16; ++t) {
    __syncthreads();
    *(uint4*)ksw = k0r;
    *(uint4*)(ksw + 32 * LSK) = k1r;
    *(uint4*)vtw = v0r;
    *(uint4*)(vtw + 32 * LSK) = v1r;
    __syncthreads();
    if (t < 15) {
      const unsigned short* kgn = kg + (size_t)(kt0 + t + 1) * 64 * HDIM;
      const unsigned short* vgn = vg + (kt0 + t + 1) * 64;
      k0r = *(const uint4*)(kgn);
      k1r = *(const uint4*)(kgn + 32 * HDIM);
      v0r = *(const uint4*)(vgn);
      v1r = *(const uint4*)(vgn + (size_t)32 * S_TOK);
    }

#pragma unroll
    for (int kt = 0; kt < 4; ++kt) {
      short8 kf0 = *(const short8*)(&Ks[(kt * 16 + l16) * LSK + quad * 8]);
      short8 kf1 = *(const short8*)(&Ks[(kt * 16 + l16) * LSK + 32 + quad * 8]);
#pragma unroll
      for (int mt = 0; mt < 4; ++mt) {
        floatx4 c = (floatx4){0.f, 0.f, 0.f, 0.f};
        c = __builtin_amdgcn_mfma_f32_16x16x32_bf16(kf0, qf[mt][0], c, 0, 0, 0);
        c = __builtin_amdgcn_mfma_f32_16x16x32_bf16(kf1, qf[mt][1], c, 0, 0, 0);
        float p0 = __builtin_amdgcn_exp2f(c[0]);
        float p1 = __builtin_amdgcn_exp2f(c[1]);
        float p2 = __builtin_amdgcn_exp2f(c[2]);
        float p3 = __builtin_amdgcn_exp2f(c[3]);
        lsum[mt] += (p0 + p1) + (p2 + p3);
        uint2 pk;
        pk.x = pack_bf16(p0, p1);
        pk.y = pack_bf16(p2, p3);
        *(uint2*)&pw[(mt * 16 + l16) * LSK + kt * 16 + quad * 4] = pk;
      }
    }

    short8 pf[4][2];
#pragma unroll
    for (int mt = 0; mt < 4; ++mt) {
      pf[mt][0] = *(const short8*)(&pw[(mt * 16 + l16) * LSK + quad * 8]);
      pf[mt][1] = *(const short8*)(&pw[(mt * 16 + l16) * LSK + 32 + quad * 8]);
    }
#pragma unroll
    for (int nt = 0; nt < 4; ++nt) {
      short8 vf0 = *(const short8*)(&Vt[(nt * 16 + l16) * LSK + quad * 8]);
      short8 vf1 = *(const short8*)(&Vt[(nt * 16 + l16) * LSK + 32 + quad * 8]);
#pragma unroll
      for (int mt = 0; mt < 4; ++mt) {
        O[mt][nt] = __builtin_amdgcn_mfma_f32_16x16x32_bf16(pf[mt][0], vf0, O[mt][nt], 0, 0, 0);
        O[mt][nt] = __builtin_amdgcn_mfma_f32_16x16x32_bf16(pf[mt][1], vf1, O[mt][nt], 0, 0, 0);
      }
    }
  }

  const int b = bh >> 2, h = bh & 3;
  unsigned short* op_s = op + (size_t)split * 2097152;
  float* lp_s = lp + (size_t)split * 32768;
#pragma unroll
  for (int mt = 0; mt < 4; ++mt) {
    float ls = lsum[mt];
    ls += __shfl_xor(ls, 16);
    ls += __shfl_xor(ls, 32);
    if (quad == 0)
      lp_s[bh * S_TOK + q0 + wave * 64 + mt * 16 + l16] = ls;
#pragma unroll
    for (int r = 0; r < 4; ++r) {
      int row = q0 + wave * 64 + mt * 16 + quad * 4 + r;
#pragma unroll
      for (int nt = 0; nt < 4; ++nt)
        op_s[((size_t)(b * S_TOK + row)) * CDIM + h * HDIM + nt * 16 + l16] =
            f2bf(O[mt][nt][r]);
    }
  }
}

// merged A-chunk: 4 ushorts = sum of 4 split partials * (1/l)
__device__ inline uint2 merge4(const unsigned short* op, size_t off, float rinv) {
  float s0 = 0.f, s1 = 0.f, s2 = 0.f, s3 = 0.f;
#pragma unroll
  for (int sp = 0; sp < 4; ++sp) {
    uint2 u = *(const uint2*)(op + (size_t)sp * 2097152 + off);
    s0 += bf2f((unsigned short)(u.x & 0xffff));
    s1 += bf2f((unsigned short)(u.x >> 16));
    s2 += bf2f((unsigned short)(u.y & 0xffff));
    s3 += bf2f((unsigned short)(u.y >> 16));
  }
  uint2 r;
  r.x = pack_bf16(s0 * rinv, s1 * rinv);
  r.y = pack_bf16(s2 * rinv, s3 * rinv);
  return r;
}

// ---------------- Kernel 3: merge + out projection + LayerNorm ---------------
// Block: 32 tokens x 256 c_out (full); B staged directly from fp32 out_w.
__global__ __launch_bounds__(256) void out_ln_gemm_kernel(
    const unsigned short* __restrict__ op, const float* __restrict__ lp,
    const float* __restrict__ ow, const float* __restrict__ obias,
    const float* __restrict__ lng, const float* __restrict__ lnb,
    float* __restrict__ out) {
  __shared__ __align__(16) unsigned short As[32 * LDA];
  __shared__ __align__(16) unsigned short Bs[256 * LDA];
  __shared__ __align__(16) float ys[32 * LDY];
  __shared__ float rsum[128];  // [tok_l][h]
  const int tid = threadIdx.x;
  const int wave = tid >> 6, lane = tid & 63;
  const int quad = lane >> 4, l16 = lane & 15;
  const int tok0 = blockIdx.x * 32;  // global token (b folded)

  if (tid < 128) {
    int t = tid >> 2, h = tid & 3;
    int bb = tok0 >> 12;
    int idx = (bb * 4 + h) * 4096 + (tok0 & 4095) + t;
    rsum[tid] =
        1.0f / (lp[idx] + lp[32768 + idx] + lp[65536 + idx] + lp[98304 + idx]);
  }
  __syncthreads();

  // A: 32 rows x 8 4-ushort chunks
  const int ar = tid >> 3, ac = tid & 7;
  const size_t abase = (size_t)(tok0 + ar) * CDIM + ac * 4;
  unsigned short* wAp = &As[ar * LDA + ac * 4];
  // B: 64-row groups x 4, thread covers rows rr+64i, floats c4*8..+7
  const int rr = tid >> 2, c4 = tid & 3;
  const float* gB = ow + (size_t)rr * CDIM + c4 * 8;
  unsigned short* wBp = &Bs[rr * LDA + c4 * 8];

  floatx4 acc[2][4];
#pragma unroll
  for (int mt = 0; mt < 2; ++mt)
#pragma unroll
    for (int nt = 0; nt < 4; ++nt) acc[mt][nt] = (floatx4){0.f, 0.f, 0.f, 0.f};

  uint2 ap = merge4(op, abase, rsum[(ar << 2) + (ac >> 4)]);  // ks=0: h = ac*4>>6 = 0 for ac<16 -> ac>>4==0
  float4 bpf[4][2];
#pragma unroll
  for (int i = 0; i < 4; ++i) {
    bpf[i][0] = *(const float4*)(gB + (size_t)i * 64 * CDIM);
    bpf[i][1] = *(const float4*)(gB + (size_t)i * 64 * CDIM + 4);
  }

  for (int ks = 0; ks < 8; ++ks) {
    __syncthreads();
    *(uint2*)wAp = ap;
#pragma unroll
    for (int i = 0; i < 4; ++i) {
      uint2 u0, u1;
      u0.x = pack_bf16(bpf[i][0].x, bpf[i][0].y);
      u0.y = pack_bf16(bpf[i][0].z, bpf[i][0].w);
      u1.x = pack_bf16(bpf[i][1].x, bpf[i][1].y);
      u1.y = pack_bf16(bpf[i][1].z, bpf[i][1].w);
      unsigned short* w = wBp + i * 64 * LDA;
      *(uint2*)w = u0;
      *(uint2*)(w + 4) = u1;
    }
    __syncthreads();
    if (ks < 7) {
      int off = (ks + 1) * 32;
      int ch = off + ac * 4;  // channel of this thread's A chunk
      ap = merge4(op, abase + off, rsum[(ar << 2) + (ch >> 6)]);
#pragma unroll
      for (int i = 0; i < 4; ++i) {
        bpf[i][0] = *(const float4*)(gB + (size_t)i * 64 * CDIM + off);
        bpf[i][1] = *(const float4*)(gB + (size_t)i * 64 * CDIM + off + 4);
      }
    }
    short8 af[2], bf[4];
#pragma unroll
    for (int mt = 0; mt < 2; ++mt)
      af[mt] = *(const short8*)&As[(mt * 16 + l16) * LDA + quad * 8];
#pragma unroll
    for (int nt = 0; nt < 4; ++nt)
      bf[nt] = *(const short8*)&Bs[(wave * 64 + nt * 16 + l16) * LDA + quad * 8];
#pragma unroll
    for (int mt = 0; mt < 2; ++mt)
#pragma unroll
      for (int nt = 0; nt < 4; ++nt)
        acc[mt][nt] = __builtin_amdgcn_mfma_f32_16x16x32_bf16(af[mt], bf[nt], acc[mt][nt], 0, 0, 0);
  }

#pragma unroll
  for (int mt = 0; mt < 2; ++mt)
#pragma unroll
    for (int nt = 0; nt < 4; ++nt) {
      int c = wave * 64 + nt * 16 + l16;
      float bo = obias[c];
#pragma unroll
      for (int r = 0; r < 4; ++r)
        ys[(mt * 16 + quad * 4 + r) * LDY + c] = acc[mt][nt][r] + bo;
    }
  __syncthreads();

  // LayerNorm: 8 lanes per token
  const int gtok = tid >> 3, l8 = tid & 7;
  float sum = 0.f, ssq = 0.f;
#pragma unroll
  for (int i = 0; i < 32; ++i) {
    float v = ys[gtok * LDY + i * 8 + l8];
    sum += v;
    ssq += v * v;
  }
  sum += __shfl_xor(sum, 1); ssq += __shfl_xor(ssq, 1);
  sum += __shfl_xor(sum, 2); ssq += __shfl_xor(ssq, 2);
  sum += __shfl_xor(sum, 4); ssq += __shfl_xor(ssq, 4);
  float mu = sum * (1.f / 256.f);
  float var = ssq * (1.f / 256.f) - mu * mu;
  float rstd = rsqrtf(var + 1e-5f);
  const int b2 = tok0 >> 12;
  const int sl = (tok0 & 4095) + gtok;
#pragma unroll
  for (int i = 0; i < 32; ++i) {
    int c = i * 8 + l8;
    float v = ys[gtok * LDY + c];
    out[(((size_t)(b2 * CDIM + c)) << 12) + sl] = (v - mu) * rstd * lng[c] + lnb[c];
  }
}

extern "C" void kernel_launch(void* const* d_in, const int* in_sizes, int n_in,
                              void* d_out, int out_size, void* d_ws, size_t ws_size,
                              hipStream_t stream) {
  const float* x = (const float*)d_in[0];
  const float* ipw = (const float*)d_in[1];
  const float* ipb = (const float*)d_in[2];
  const float* ow = (const float*)d_in[3];
  const float* ob = (const float*)d_in[4];
  const float* lng = (const float*)d_in[5];
  const float* lnb = (const float*)d_in[6];
  float* out = (float*)d_out;
  // workspace (ushort units), total ~29.9 MiB:
  unsigned short* q16 = (unsigned short*)d_ws;       // 2097152
  unsigned short* k16 = q16 + 2097152;               // 2097152
  unsigned short* vt16 = k16 + 2097152;              // 2097152
  unsigned short* op = vt16 + 2097152;               // 4 x 2097152 (ab-layout partials)
  float* lp = (float*)(op + 8388608);                // 4 x 32768 fp32

  qkv_gemm_kernel<<<dim3(4, 64, 2), 256, 0, stream>>>(x, ipw, ipb, q16, k16, vt16);
  attn_kernel<<<dim3(16, 8, 4), 256, 0, stream>>>(q16, k16, vt16, op, lp);
  out_ln_gemm_kernel<<<256, 256, 0, stream>>>(op, lp, ow, ob, lng, lnb, out);
}